// Round 7
// baseline (204.450 us; speedup 1.0000x reference)
//
#include <hip/hip_runtime.h>

#define N_SP 16384
#define C_DIM 128
#define K_DIM 32
#define TILEN 256                 // n per block (one tile)
#define NBX   (N_SP / TILEN)      // 64 blocks along n

typedef short short8 __attribute__((ext_vector_type(8)));
typedef float f32x16 __attribute__((ext_vector_type(16)));

__device__ __forceinline__ unsigned f2bfu(float f){
    return (__float_as_uint(f) + 0x8000u) >> 16;   // cheap RN to bf16 bits
}
__device__ __forceinline__ unsigned short f2bf(float f){
    return (unsigned short)f2bfu(f);
}

// swizzled index into a [row][256] ushort tile: XOR n-bits 3..6 with row&15
// -> 8-ushort groups stay contiguous (b128 legal); 32 rows -> 16 slots -> 2-way (free)
#define SWZ(row, n) (((row) << 8) + ((n) ^ (((row) & 15) << 3)))

union FragU { int i[4]; short8 s; };

__global__ __launch_bounds__(256, 2) void enc_main(
    const float* __restrict__ x,              // [B][C][N]
    const unsigned short* __restrict__ cwt2b, // [K][C] bf16 of -2*scale[k]*cw[k][c]
    const float* __restrict__ combo,          // [K][2] = {scale[k], scale[k]*||cw_k||^2}
    float* __restrict__ wxacc,                // [B][K][C] (zeroed)
    float* __restrict__ wsacc)                // [B][K]    (zeroed)
{
    __shared__ unsigned short xs[C_DIM * TILEN];   // bf16 x[c][n'] swizzled (64 KB)
    __shared__ unsigned short aws[K_DIM * TILEN];  // bf16 aw[k][n'] swizzled (16 KB)

    const int t   = threadIdx.x;   // 0..255; thread owns n-column n0 + t
    const int b   = blockIdx.y;
    const int w   = t >> 6;        // wave 0..3: owns cols 64w..64w+63, c-strip 32w..
    const int hi  = (t >> 5) & 1;
    const int l31 = t & 31;

    const float* xb = x + (size_t)b * C_DIM * N_SP;
    const int n0 = blockIdx.x * TILEN;

    // held codeword A-fragments: lane l31 = k-row, hi picks 8-c half of each 16-chunk
    short8 cwA[8];
#pragma unroll
    for (int ksg = 0; ksg < 8; ++ksg)
        cwA[ksg] = *(const short8*)(const void*)(cwt2b + l31 * C_DIM + ksg * 16 + hi * 8);

    short8 ones;
#pragma unroll
    for (int i = 0; i < 8; ++i) ones[i] = (short)0x3F80;  // bf16 1.0

    // ---- phase 1 + S: stream x (depth-2), fp32 x2, stage bf16, S via MFMA ----
    const float* xp = xb + n0 + t;     // 4 waves' instrs cover 1KB contiguous per c-row

    f32x16 sA, sB;                     // S[k][n]: group0 cols 64w+l31, group1 64w+32+l31
#pragma unroll
    for (int i = 0; i < 16; ++i){ sA[i] = 0.f; sB[i] = 0.f; }

    float x2 = 0.f;
    int xr[32];                        // packed bf16 pairs of this column, current c-half

#pragma unroll
    for (int h = 0; h < 2; ++h){
        const int cb = h * 64;
        float cur[8], nx1[8];
#pragma unroll
        for (int j = 0; j < 8; ++j) cur[j] = xp[(cb + j) * N_SP];
#pragma unroll
        for (int j = 0; j < 8; ++j) nx1[j] = xp[(cb + 8 + j) * N_SP];

#pragma unroll
        for (int g = 0; g < 8; ++g){
            float nx2[8];
            if (g < 6){
#pragma unroll
                for (int j = 0; j < 8; ++j) nx2[j] = xp[(cb + (g + 2) * 8 + j) * N_SP];
            } else {
#pragma unroll
                for (int j = 0; j < 8; ++j) nx2[j] = 0.f;
            }
#pragma unroll
            for (int j = 0; j < 8; j += 2){
                const int cl = g * 8 + j;      // local c in half (0..63)
                const int c  = cb + cl;
                const float a0 = cur[j], a1 = cur[j + 1];
                x2 = fmaf(a0, a0, x2);
                x2 = fmaf(a1, a1, x2);
                const unsigned u0 = f2bfu(a0), u1 = f2bfu(a1);
                xs[SWZ(c,     t)] = (unsigned short)u0;
                xs[SWZ(c + 1, t)] = (unsigned short)u1;
                xr[cl >> 1] = (int)(u0 | (u1 << 16));
            }
            if (g < 7){
#pragma unroll
                for (int j = 0; j < 8; ++j){ cur[j] = nx1[j]; nx1[j] = nx2[j]; }
            }
        }

        // S += cwt2 * x via MFMA; B-frags built from registers via intra-wave lane-swap
#pragma unroll
        for (int kl = 0; kl < 4; ++kl){
            FragU f0, f1;
#pragma unroll
            for (int d = 0; d < 4; ++d){
                const int L  = xr[kl * 8 + d];        // c = kl*16 + 2d,2d+1
                const int H  = xr[kl * 8 + 4 + d];    // c = kl*16+8 + 2d,2d+1
                const int sl = __shfl_xor(L, 32);
                const int sh = __shfl_xor(H, 32);
                f0.i[d] = hi ? sh : L;   // col 64w+l31    : owner lane l31
                f1.i[d] = hi ? H  : sl;  // col 64w+32+l31 : owner lane 32+l31
            }
            sA = __builtin_amdgcn_mfma_f32_32x32x16_bf16(cwA[h*4+kl], f0.s, sA, 0,0,0);
            sB = __builtin_amdgcn_mfma_f32_32x32x16_bf16(cwA[h*4+kl], f1.s, sB, 0,0,0);
        }
    }

    // ---- phase 2: softmax over k on the MFMA D-layout ----
    float csx[16], csy[16];
#pragma unroll
    for (int q = 0; q < 16; ++q){
        const int row = (q & 3) + 8 * (q >> 2) + 4 * hi;
        csx[q] = combo[2 * row];
        csy[q] = combo[2 * row + 1];
    }
    const float x2o  = __shfl_xor(x2, 32);
    const float x2g0 = hi ? x2o : x2;   // x2[col 64w+l31]
    const float x2g1 = hi ? x2 : x2o;   // x2[col 64w+32+l31]

    {   // group 0: cols 64w + l31
        float arg[16]; float ml = -3.4e38f;
#pragma unroll
        for (int q = 0; q < 16; ++q){
            arg[q] = fmaf(csx[q], x2g0, sA[q] + csy[q]);
            ml = fmaxf(ml, arg[q]);
        }
        const float mm = fmaxf(ml, __shfl_xor(ml, 32));
        float sum = 0.f;
#pragma unroll
        for (int q = 0; q < 16; ++q){ float p = __expf(arg[q] - mm); arg[q] = p; sum += p; }
        sum += __shfl_xor(sum, 32);
        const float r = 1.f / sum;
#pragma unroll
        for (int q = 0; q < 16; ++q){
            const int row = (q & 3) + 8 * (q >> 2) + 4 * hi;
            aws[SWZ(row, 64 * w + l31)] = f2bf(arg[q] * r);
        }
    }
    {   // group 1: cols 64w + 32 + l31
        float arg[16]; float ml = -3.4e38f;
#pragma unroll
        for (int q = 0; q < 16; ++q){
            arg[q] = fmaf(csx[q], x2g1, sB[q] + csy[q]);
            ml = fmaxf(ml, arg[q]);
        }
        const float mm = fmaxf(ml, __shfl_xor(ml, 32));
        float sum = 0.f;
#pragma unroll
        for (int q = 0; q < 16; ++q){ float p = __expf(arg[q] - mm); arg[q] = p; sum += p; }
        sum += __shfl_xor(sum, 32);
        const float r = 1.f / sum;
#pragma unroll
        for (int q = 0; q < 16; ++q){
            const int row = (q & 3) + 8 * (q >> 2) + 4 * hi;
            aws[SWZ(row, 64 * w + 32 + l31)] = f2bf(arg[q] * r);
        }
    }

    __syncthreads();   // the ONLY barrier: xs/aws complete -> phase D reads all of it

    // ---- phase D: wx[k][c] += aw[k][n] * x[n][c]; wave w owns c-strip 32w..32w+31 ----
    f32x16 acc, accS;
#pragma unroll
    for (int i = 0; i < 16; ++i){ acc[i] = 0.f; accS[i] = 0.f; }
    const int cmy = 32 * w + l31;

#pragma unroll
    for (int ks = 0; ks < 16; ++ks){           // n = 256 -> 16 k-steps of 16
        const int n8 = ks * 16 + hi * 8;
        short8 af = *(const short8*)(const void*)&aws[SWZ(l31, n8)];
        short8 bf = *(const short8*)(const void*)&xs[SWZ(cmy, n8)];
        acc = __builtin_amdgcn_mfma_f32_32x32x16_bf16(af, bf, acc, 0, 0, 0);
        if ((ks >> 2) == w)                    // wsum: wave w covers ks 4w..4w+3
            accS = __builtin_amdgcn_mfma_f32_32x32x16_bf16(af, ones, accS, 0, 0, 0);
    }

    // ---- epilogue: atomic-reduce block partials to global ----
    float* wxb = wxacc + (size_t)b * K_DIM * C_DIM;
#pragma unroll
    for (int rg = 0; rg < 16; ++rg){
        const int row = (rg & 3) + 8 * (rg >> 2) + 4 * hi;  // verified D layout
        atomicAdd(&wxb[row * C_DIM + cmy], acc[rg]);
    }
    if (l31 == 0){
#pragma unroll
        for (int rg = 0; rg < 16; ++rg){
            const int row = (rg & 3) + 8 * (rg >> 2) + 4 * hi;
            atomicAdd(&wsacc[b * K_DIM + row], accS[rg]);
        }
    }
}

__global__ void enc_zero(float* __restrict__ p, int n){
    const int i = blockIdx.x * 256 + threadIdx.x;
    if (i < n) p[i] = 0.f;
}

__global__ void enc_prep(const float* __restrict__ cw, const float* __restrict__ scale,
                         unsigned short* __restrict__ cwt2b, float* __restrict__ combo){
    const int t = threadIdx.x;  // 128 threads; t = c
    for (int k = 0; k < K_DIM; ++k)
        cwt2b[k * C_DIM + t] = f2bf(-2.f * scale[k] * cw[k * C_DIM + t]);
    if (t < K_DIM){
        float s = 0.f;
        for (int c = 0; c < C_DIM; ++c){
            float v = cw[t * C_DIM + c];
            s = fmaf(v, v, s);
        }
        combo[2 * t]     = scale[t];
        combo[2 * t + 1] = scale[t] * s;
    }
}

__global__ void enc_final(const float* __restrict__ wxacc, const float* __restrict__ wsacc,
                          const float* __restrict__ cw, float* __restrict__ out){
    const int i  = blockIdx.x * 256 + threadIdx.x;  // B*K*C = 131072
    const int c  = i & (C_DIM - 1);
    const int kk = (i >> 7) & (K_DIM - 1);
    const int bk = i >> 7;
    out[i] = wxacc[i] - wsacc[bk] * cw[kk * C_DIM + c];
}

extern "C" void kernel_launch(void* const* d_in, const int* in_sizes, int n_in,
                              void* d_out, int out_size, void* d_ws, size_t ws_size,
                              hipStream_t stream){
    (void)in_sizes; (void)n_in; (void)out_size; (void)ws_size;
    const float* x     = (const float*)d_in[0];
    const float* cw    = (const float*)d_in[1];
    const float* scale = (const float*)d_in[2];
    float* out = (float*)d_out;

    float* wxacc = (float*)d_ws;                            // 131072 f32
    float* wsacc = wxacc + 32 * 32 * C_DIM;                 // 1024 f32
    float* combo = wsacc + 32 * 32;                         // 64 f32
    unsigned short* cwt2b = (unsigned short*)(combo + 64);  // 4096 ushort

    const int nz = 32 * 32 * C_DIM + 32 * 32;
    enc_zero<<<(nz + 255) / 256, 256, 0, stream>>>(wxacc, nz);
    enc_prep<<<1, 128, 0, stream>>>(cw, scale, cwt2b, combo);
    enc_main<<<dim3(NBX, 32), 256, 0, stream>>>(x, cwt2b, combo, wxacc, wsacc);
    enc_final<<<512, 256, 0, stream>>>(wxacc, wsacc, cw, out);
}